// Round 3
// baseline (294.821 us; speedup 1.0000x reference)
//
#include <hip/hip_runtime.h>

// Problem constants: B=4, GX=480, GY=360, C_IN=64, C_OUT=32, N=480000
#define GXGY  172800        // GX*GY (multiple of 64: blocks never straddle batch)
#define NSEG  691200        // B*GX*GY
#define CIN   64
#define COUT  32
#define VPB   64            // voxels per block
#define PSTR  65            // pooled LDS stride: phase-2 bank=(lv+k)%32 -> 2-way = free
#define NTILE 675           // NSEG / 1024 scan tiles

// ---------------------------------------------------------------------------
// R6 (3rd submit; rounds 1-2 died in infra before execution): CSR counting
// sort replaces linked-list chase. count -> tile-scan -> totals-scan -> fill
// -> pool(gather from contiguous CSR spans staged through LDS; every fea row
// load independent).
// Workspace: cnt[NSEG] + tsum[1024] + csr[N] = 4.69 MB (same as head+next).
// ---------------------------------------------------------------------------

__global__ __launch_bounds__(256) void count_kernel(
    const int* __restrict__ ind,   // [N,2]
    const int* __restrict__ bidx,  // [N]
    int*       __restrict__ cnt,   // [NSEG], zeroed
    int N)
{
    int i = blockIdx.x * 256 + threadIdx.x;
    if (i >= N) return;
    int2 xy = ((const int2*)ind)[i];
    int seg = bidx[i] * GXGY + xy.x * 360 + xy.y;
    atomicAdd(&cnt[seg], 1);
}

// Per-1024-element tile: exclusive scan IN PLACE over cnt, tile total -> tsum.
__global__ __launch_bounds__(256) void scan_tile_kernel(
    int* __restrict__ cnt, int* __restrict__ tsum)
{
    int t = threadIdx.x;
    int base = blockIdx.x * 256 + t;          // int4 granularity
    int4 c = ((const int4*)cnt)[base];
    int s = c.x + c.y + c.z + c.w;

    int lane = t & 63, wid = t >> 6;
    int v = s;
    #pragma unroll
    for (int d = 1; d < 64; d <<= 1) {        // wave inclusive scan
        int u = __shfl_up(v, d);
        if (lane >= d) v += u;
    }
    __shared__ int wsum[4];
    if (lane == 63) wsum[wid] = v;
    __syncthreads();
    int wbase = 0;
    #pragma unroll
    for (int w = 0; w < 3; ++w) if (w < wid) wbase += wsum[w];

    int excl = wbase + v - s;                 // exclusive prefix of this thread
    int4 o; o.x = excl; o.y = o.x + c.x; o.z = o.y + c.y; o.w = o.z + c.z;
    ((int4*)cnt)[base] = o;
    if (t == 255) tsum[blockIdx.x] = excl + s;  // block total
}

// Exclusive scan of the 675 tile totals, in place, one block.
__global__ __launch_bounds__(256) void scan_totals_kernel(int* __restrict__ tsum)
{
    __shared__ int buf[1024];
    int t = threadIdx.x;
    for (int j = t; j < 1024; j += 256) buf[j] = (j < NTILE) ? tsum[j] : 0;
    __syncthreads();
    for (int d = 1; d < 1024; d <<= 1) {
        int vals[4];
        #pragma unroll
        for (int k = 0; k < 4; ++k) { int j = t + k * 256; vals[k] = (j >= d) ? buf[j - d] : 0; }
        __syncthreads();
        #pragma unroll
        for (int k = 0; k < 4; ++k) { int j = t + k * 256; buf[j] += vals[k]; }
        __syncthreads();
    }
    for (int j = t; j < NTILE; j += 256) tsum[j] = (j == 0) ? 0 : buf[j - 1];
}

// Scatter point ids into CSR order. After this kernel:
//   cnt[v] + tsum[v>>10] == inclusive END offset of voxel v's span.
__global__ __launch_bounds__(256) void fill_kernel(
    const int* __restrict__ ind,
    const int* __restrict__ bidx,
    int*       __restrict__ cnt,   // tile-local exclusive scan (advanced as cursor)
    const int* __restrict__ tsum,  // tile prefix
    int*       __restrict__ csr,   // [N]
    int N)
{
    int i = blockIdx.x * 256 + threadIdx.x;
    if (i >= N) return;
    int2 xy = ((const int2*)ind)[i];
    int seg = bidx[i] * GXGY + xy.x * 360 + xy.y;
    int pos = atomicAdd(&cnt[seg], 1) + tsum[seg >> 10];
    csr[pos] = i;
}

// ---------------------------------------------------------------------------
// Fused pool+compress. Block = 256 threads = 64 voxels, 16 voxels per wave.
// Phase 1: wave's CSR span is CONTIGUOUS -> one coalesced load stages the
//   point ids into LDS; all fea-row loads are then independent (no chase).
//   Subgroup (16 lanes) owns 4 voxels; lane sl loads float4 channel slice.
// Phase 2: unchanged from R5 (verified): thread (lv=tid&63, g=tid>>6) ->
//   channels g*8..g*8+7; W via wave-uniform scalar loads; sP 2-way bank=free.
// ---------------------------------------------------------------------------
__global__ __launch_bounds__(256) void pool_compress_kernel(
    const float* __restrict__ fea,   // [N, 64]
    const int*   __restrict__ cnt,   // post-fill: per-voxel inclusive end (tile-local)
    const int*   __restrict__ tsum,  // tile prefix
    const int*   __restrict__ csr,   // [N] point ids grouped by voxel
    const float* __restrict__ W,     // [64, 32] row-major
    const float* __restrict__ bias,  // [32]
    float*       __restrict__ out)   // [B, 32, GX, GY]
{
    __shared__ float sP[VPB * PSTR];   // 16.25 KB pooled rows
    __shared__ int   sLen[VPB];
    __shared__ int   sIdx[4][64];      // per-wave staged CSR entries

    int tid  = threadIdx.x;
    int wid  = tid >> 6;
    int lane = tid & 63;
    int sub  = lane >> 4;    // subgroup 0..3
    int sl   = lane & 15;    // lane within subgroup

    int vbase = blockIdx.x * VPB;
    int v0    = vbase + wid * 16;

    // o(lane) = inclusive end of voxel (v0-1+lane); o(0)=start of first voxel.
    int o = 0;
    if (lane < 17) {
        int vv = v0 - 1 + lane;
        o = (vv < 0) ? 0 : (cnt[vv] + tsum[vv >> 10]);
    }
    int onext = __shfl(o, (lane + 1) & 63);
    if (lane < 16) sLen[wid * 16 + lane] = onext - o;

    // Stage this wave's contiguous CSR span (typically ~15 ids) into LDS.
    int ws0 = __shfl(o, 0);
    int wsE = __shfl(o, 16);
    int cw  = wsE - ws0;
    if (lane < min(cw, 64)) sIdx[wid][lane] = csr[ws0 + lane];

    int stt[4], len[4];
    #pragma unroll
    for (int q = 0; q < 4; ++q) {
        int a = __shfl(o, q * 4 + sub);
        int b = __shfl(o, q * 4 + sub + 1);
        stt[q] = a; len[q] = b - a;
    }
    int maxlen = max(max(len[0], len[1]), max(len[2], len[3]));

    // ---- Phase 1: independent gather, 4 voxels per subgroup ----
    float4 m[4];
    #pragma unroll
    for (int q = 0; q < 4; ++q) if (len[q] > 0) {
        int off = stt[q] - ws0;
        int id  = (off < 64) ? sIdx[wid][off] : csr[stt[q]];
        m[q] = ((const float4*)(fea + (size_t)id * CIN))[sl];
    }
    for (int r = 1; r < maxlen; ++r) {
        #pragma unroll
        for (int q = 0; q < 4; ++q) if (r < len[q]) {
            int off = stt[q] - ws0 + r;
            int id  = (off < 64) ? sIdx[wid][off] : csr[stt[q] + r];
            float4 t = ((const float4*)(fea + (size_t)id * CIN))[sl];
            m[q].x = fmaxf(m[q].x, t.x);
            m[q].y = fmaxf(m[q].y, t.y);
            m[q].z = fmaxf(m[q].z, t.z);
            m[q].w = fmaxf(m[q].w, t.w);
        }
    }
    #pragma unroll
    for (int q = 0; q < 4; ++q) if (len[q] > 0) {
        int lv = wid * 16 + q * 4 + sub;
        float* dst = &sP[lv * PSTR + sl * 4];
        dst[0] = m[q].x; dst[1] = m[q].y; dst[2] = m[q].z; dst[3] = m[q].w;
    }
    __syncthreads();

    // ---- Phase 2: 64x8 matvec per thread, W via wave-uniform scalar loads ----
    int lv = lane;                                   // voxel within block
    int g  = __builtin_amdgcn_readfirstlane(wid);    // wave-uniform SGPR
    int b  = vbase / GXGY;                           // uniform per block
    int rem = vbase - b * GXGY + lv;

    const float* Wg = W + g * 8;
    const float* bg = bias + g * 8;

    float res[8];
    if (sLen[lv] > 0) {
        float acc[8];
        #pragma unroll
        for (int c = 0; c < 8; ++c) acc[c] = bg[c];
        #pragma unroll 16
        for (int k = 0; k < CIN; ++k) {
            float p = sP[lv * PSTR + k];             // 2-way bank = free
            #pragma unroll
            for (int c = 0; c < 8; ++c)
                acc[c] = fmaf(p, Wg[k * COUT + c], acc[c]);
        }
        #pragma unroll
        for (int c = 0; c < 8; ++c) res[c] = fmaxf(acc[c], 0.0f);
    } else {
        #pragma unroll
        for (int c = 0; c < 8; ++c) res[c] = 0.0f;
    }

    float* op = out + (size_t)b * COUT * GXGY + (size_t)g * 8 * GXGY + rem;
    #pragma unroll
    for (int c = 0; c < 8; ++c) op[c * GXGY] = res[c];
}

extern "C" void kernel_launch(void* const* d_in, const int* in_sizes, int n_in,
                              void* d_out, int out_size, void* d_ws, size_t ws_size,
                              hipStream_t stream)
{
    const float* fea  = (const float*)d_in[0];
    const int*   ind  = (const int*)d_in[1];
    const int*   bidx = (const int*)d_in[2];
    const float* W    = (const float*)d_in[3];
    const float* bias = (const float*)d_in[4];
    float*       out  = (float*)d_out;

    int N = in_sizes[0] / CIN;  // 480000

    int* cnt  = (int*)d_ws;            // NSEG ints (2.76 MB)
    int* tsum = cnt + NSEG;            // 1024 ints (675 used)
    int* csr  = tsum + 1024;           // N ints (1.92 MB)

    hipMemsetAsync(cnt, 0, (size_t)NSEG * sizeof(int), stream);
    count_kernel<<<(N + 255) / 256, 256, 0, stream>>>(ind, bidx, cnt, N);
    scan_tile_kernel<<<NTILE, 256, 0, stream>>>(cnt, tsum);
    scan_totals_kernel<<<1, 256, 0, stream>>>(tsum);
    fill_kernel<<<(N + 255) / 256, 256, 0, stream>>>(ind, bidx, cnt, tsum, csr, N);
    pool_compress_kernel<<<NSEG / VPB, 256, 0, stream>>>(fea, cnt, tsum, csr, W, bias, out);
}

// Round 4
// 292.104 us; speedup vs baseline: 1.0093x; 1.0093x over previous
//
#include <hip/hip_runtime.h>

// Problem constants: B=4, GX=480, GY=360, C_IN=64, C_OUT=32, N=480000
#define GXGY  172800        // GX*GY (multiple of 64: blocks never straddle batch)
#define NSEG  691200        // B*GX*GY
#define CIN   64
#define COUT  32
#define VPB   64            // voxels per block
#define PSTR  65            // pooled LDS stride: phase-2 bank=(lv+k)%32 -> 2-way = free
#define NTILE 675           // NSEG / 1024 scan tiles

// ---------------------------------------------------------------------------
// R7: CSR kept, but pool phase-1 merge loop is unrolled 4 rounds x 4 chains
//     (16 independent loads in flight, one wait batch) with CLAMPED offsets:
//     out-of-range slots reload the chain's own last point (idempotent for
//     max). Kills the per-round vmcnt serialization that made R6 slow.
//     cnt[] is made ABSOLUTE (add_base kernel) -> shorter prologue, and
//     fill_kernel loses its dependent tsum load.
// Workspace: cnt[NSEG] + tsum[1024] + csr[N] = 4.69 MB.
// ---------------------------------------------------------------------------

__global__ __launch_bounds__(256) void count_kernel(
    const int* __restrict__ ind,   // [N,2]
    const int* __restrict__ bidx,  // [N]
    int*       __restrict__ cnt,   // [NSEG], zeroed
    int N)
{
    int i = blockIdx.x * 256 + threadIdx.x;
    if (i >= N) return;
    int2 xy = ((const int2*)ind)[i];
    int seg = bidx[i] * GXGY + xy.x * 360 + xy.y;
    atomicAdd(&cnt[seg], 1);   // no return -> fire-and-forget
}

// Per-1024-element tile: exclusive scan IN PLACE over cnt, tile total -> tsum.
__global__ __launch_bounds__(256) void scan_tile_kernel(
    int* __restrict__ cnt, int* __restrict__ tsum)
{
    int t = threadIdx.x;
    int base = blockIdx.x * 256 + t;          // int4 granularity
    int4 c = ((const int4*)cnt)[base];
    int s = c.x + c.y + c.z + c.w;

    int lane = t & 63, wid = t >> 6;
    int v = s;
    #pragma unroll
    for (int d = 1; d < 64; d <<= 1) {        // wave inclusive scan
        int u = __shfl_up(v, d);
        if (lane >= d) v += u;
    }
    __shared__ int wsum[4];
    if (lane == 63) wsum[wid] = v;
    __syncthreads();
    int wbase = 0;
    #pragma unroll
    for (int w = 0; w < 3; ++w) if (w < wid) wbase += wsum[w];

    int excl = wbase + v - s;                 // exclusive prefix of this thread
    int4 o; o.x = excl; o.y = o.x + c.x; o.z = o.y + c.y; o.w = o.z + c.z;
    ((int4*)cnt)[base] = o;
    if (t == 255) tsum[blockIdx.x] = excl + s;  // block total
}

// Exclusive scan of the 675 tile totals, in place, one block.
__global__ __launch_bounds__(256) void scan_totals_kernel(int* __restrict__ tsum)
{
    __shared__ int buf[1024];
    int t = threadIdx.x;
    for (int j = t; j < 1024; j += 256) buf[j] = (j < NTILE) ? tsum[j] : 0;
    __syncthreads();
    for (int d = 1; d < 1024; d <<= 1) {
        int vals[4];
        #pragma unroll
        for (int k = 0; k < 4; ++k) { int j = t + k * 256; vals[k] = (j >= d) ? buf[j - d] : 0; }
        __syncthreads();
        #pragma unroll
        for (int k = 0; k < 4; ++k) { int j = t + k * 256; buf[j] += vals[k]; }
        __syncthreads();
    }
    for (int j = t; j < NTILE; j += 256) tsum[j] = (j == 0) ? 0 : buf[j - 1];
}

// cnt[tile-local exclusive] += tile prefix  ->  cnt becomes ABSOLUTE exclusive.
__global__ __launch_bounds__(256) void add_base_kernel(
    int* __restrict__ cnt, const int* __restrict__ tsum)
{
    int t = tsum[blockIdx.x];                 // block-uniform -> scalar load
    int4* p = (int4*)cnt + blockIdx.x * 256 + threadIdx.x;
    int4 v = *p;
    v.x += t; v.y += t; v.z += t; v.w += t;
    *p = v;
}

// Scatter point ids into CSR order. After this kernel:
//   cnt[v] == ABSOLUTE inclusive END offset of voxel v's span.
__global__ __launch_bounds__(256) void fill_kernel(
    const int* __restrict__ ind,
    const int* __restrict__ bidx,
    int*       __restrict__ cnt,   // absolute exclusive scan (advanced as cursor)
    int*       __restrict__ csr,   // [N]
    int N)
{
    int i = blockIdx.x * 256 + threadIdx.x;
    if (i >= N) return;
    int2 xy = ((const int2*)ind)[i];
    int seg = bidx[i] * GXGY + xy.x * 360 + xy.y;
    int pos = atomicAdd(&cnt[seg], 1);
    csr[pos] = i;
}

// ---------------------------------------------------------------------------
// Fused pool+compress. Block = 256 threads = 64 voxels, 16 voxels per wave.
// Phase 1: wave's CSR span staged to LDS; merge loop unrolled 4 rounds x
//   4 chains with clamped idempotent reloads -> 16 loads per wait.
// Phase 2: unchanged (verified): thread (lv=tid&63, g=tid>>6) -> channels
//   g*8..g*8+7; W via wave-uniform scalar loads; sP 2-way bank = free.
// ---------------------------------------------------------------------------
__global__ __launch_bounds__(256) void pool_compress_kernel(
    const float* __restrict__ fea,   // [N, 64]
    const int*   __restrict__ cnt,   // absolute inclusive end per voxel
    const int*   __restrict__ csr,   // [N] point ids grouped by voxel
    const float* __restrict__ W,     // [64, 32] row-major
    const float* __restrict__ bias,  // [32]
    float*       __restrict__ out)   // [B, 32, GX, GY]
{
    __shared__ float sP[VPB * PSTR];   // 16.25 KB pooled rows
    __shared__ int   sLen[VPB];
    __shared__ int   sIdx[4][64];      // per-wave staged CSR entries

    int tid  = threadIdx.x;
    int wid  = tid >> 6;
    int lane = tid & 63;
    int sub  = lane >> 4;    // subgroup 0..3
    int sl   = lane & 15;    // lane within subgroup

    int vbase = blockIdx.x * VPB;
    int v0    = vbase + wid * 16;

    // o(lane) = absolute inclusive end of voxel (v0-1+lane); o(0)=start of first.
    int o = 0;
    if (lane < 17) {
        int vv = v0 - 1 + lane;
        o = (vv < 0) ? 0 : cnt[vv];
    }
    int onext = __shfl(o, (lane + 1) & 63);
    if (lane < 16) sLen[wid * 16 + lane] = onext - o;

    // Stage this wave's contiguous CSR span (typically ~11 ids) into LDS.
    int ws0 = __shfl(o, 0);
    int wsE = __shfl(o, 16);
    int cw  = wsE - ws0;
    if (lane < min(cw, 64)) sIdx[wid][lane] = csr[ws0 + lane];

    int stt[4], len[4];
    #pragma unroll
    for (int q = 0; q < 4; ++q) {
        int a  = __shfl(o, q * 4 + sub);
        int bb = __shfl(o, q * 4 + sub + 1);
        stt[q] = a; len[q] = bb - a;
    }
    int maxlen = max(max(len[0], len[1]), max(len[2], len[3]));

    float4 m[4];
    if (cw > 0 && cw <= 64) {
        // ---- fast path: clamped offsets, 16 loads in flight per iteration ----
        int s_[4], e_[4];
        #pragma unroll
        for (int q = 0; q < 4; ++q) {
            int b0 = stt[q] - ws0;                         // start within stage
            s_[q] = min(b0, cw - 1);                       // safe even if len==0
            int last = b0 + ((len[q] > 0) ? (len[q] - 1) : 0);
            e_[q] = min(last, cw - 1);                     // own last point
        }
        #pragma unroll
        for (int q = 0; q < 4; ++q) {
            int id = sIdx[wid][s_[q]];                     // broadcast LDS read
            m[q] = ((const float4*)(fea + (size_t)id * CIN))[sl];
        }
        for (int r = 1; r < maxlen; r += 4) {
            float4 t[4][4];
            #pragma unroll
            for (int k = 0; k < 4; ++k) {
                #pragma unroll
                for (int q = 0; q < 4; ++q) {
                    int off = min(s_[q] + r + k, e_[q]);   // clamp: reload own last
                    int id  = sIdx[wid][off];
                    t[k][q] = ((const float4*)(fea + (size_t)id * CIN))[sl];
                }
            }
            #pragma unroll
            for (int k = 0; k < 4; ++k) {
                #pragma unroll
                for (int q = 0; q < 4; ++q) {
                    m[q].x = fmaxf(m[q].x, t[k][q].x);
                    m[q].y = fmaxf(m[q].y, t[k][q].y);
                    m[q].z = fmaxf(m[q].z, t[k][q].z);
                    m[q].w = fmaxf(m[q].w, t[k][q].w);
                }
            }
        }
    } else if (cw > 64) {
        // ---- rare fallback (wave span > 64 points): global csr reads ----
        #pragma unroll
        for (int q = 0; q < 4; ++q) if (len[q] > 0) {
            int id = csr[stt[q]];
            m[q] = ((const float4*)(fea + (size_t)id * CIN))[sl];
        }
        for (int r = 1; r < maxlen; ++r) {
            #pragma unroll
            for (int q = 0; q < 4; ++q) if (r < len[q]) {
                int id = csr[stt[q] + r];
                float4 t = ((const float4*)(fea + (size_t)id * CIN))[sl];
                m[q].x = fmaxf(m[q].x, t.x);
                m[q].y = fmaxf(m[q].y, t.y);
                m[q].z = fmaxf(m[q].z, t.z);
                m[q].w = fmaxf(m[q].w, t.w);
            }
        }
    }
    #pragma unroll
    for (int q = 0; q < 4; ++q) if (len[q] > 0) {
        int lv = wid * 16 + q * 4 + sub;
        float* dst = &sP[lv * PSTR + sl * 4];
        dst[0] = m[q].x; dst[1] = m[q].y; dst[2] = m[q].z; dst[3] = m[q].w;
    }
    __syncthreads();

    // ---- Phase 2: 64x8 matvec per thread, W via wave-uniform scalar loads ----
    int lv = lane;                                   // voxel within block
    int g  = __builtin_amdgcn_readfirstlane(wid);    // wave-uniform SGPR
    int b  = vbase / GXGY;                           // uniform per block
    int rem = vbase - b * GXGY + lv;

    const float* Wg = W + g * 8;
    const float* bg = bias + g * 8;

    float res[8];
    if (sLen[lv] > 0) {
        float acc[8];
        #pragma unroll
        for (int c = 0; c < 8; ++c) acc[c] = bg[c];
        #pragma unroll 16
        for (int k = 0; k < CIN; ++k) {
            float p = sP[lv * PSTR + k];             // 2-way bank = free
            #pragma unroll
            for (int c = 0; c < 8; ++c)
                acc[c] = fmaf(p, Wg[k * COUT + c], acc[c]);
        }
        #pragma unroll
        for (int c = 0; c < 8; ++c) res[c] = fmaxf(acc[c], 0.0f);
    } else {
        #pragma unroll
        for (int c = 0; c < 8; ++c) res[c] = 0.0f;
    }

    float* op = out + (size_t)b * COUT * GXGY + (size_t)g * 8 * GXGY + rem;
    #pragma unroll
    for (int c = 0; c < 8; ++c) op[c * GXGY] = res[c];
}

extern "C" void kernel_launch(void* const* d_in, const int* in_sizes, int n_in,
                              void* d_out, int out_size, void* d_ws, size_t ws_size,
                              hipStream_t stream)
{
    const float* fea  = (const float*)d_in[0];
    const int*   ind  = (const int*)d_in[1];
    const int*   bidx = (const int*)d_in[2];
    const float* W    = (const float*)d_in[3];
    const float* bias = (const float*)d_in[4];
    float*       out  = (float*)d_out;

    int N = in_sizes[0] / CIN;  // 480000

    int* cnt  = (int*)d_ws;            // NSEG ints (2.76 MB)
    int* tsum = cnt + NSEG;            // 1024 ints (675 used)
    int* csr  = tsum + 1024;           // N ints (1.92 MB)

    hipMemsetAsync(cnt, 0, (size_t)NSEG * sizeof(int), stream);
    count_kernel<<<(N + 255) / 256, 256, 0, stream>>>(ind, bidx, cnt, N);
    scan_tile_kernel<<<NTILE, 256, 0, stream>>>(cnt, tsum);
    scan_totals_kernel<<<1, 256, 0, stream>>>(tsum);
    add_base_kernel<<<NTILE, 256, 0, stream>>>(cnt, tsum);
    fill_kernel<<<(N + 255) / 256, 256, 0, stream>>>(ind, bidx, cnt, csr, N);
    pool_compress_kernel<<<NSEG / VPB, 256, 0, stream>>>(fea, cnt, csr, W, bias, out);
}

// Round 5
// 269.252 us; speedup vs baseline: 1.0950x; 1.0849x over previous
//
#include <hip/hip_runtime.h>

// Problem constants: B=4, GX=480, GY=360, C_IN=64, C_OUT=32, N=480000
#define GXGY  172800        // GX*GY (multiple of 64: blocks never straddle batch)
#define NSEG  691200        // B*GX*GY
#define NBLK  10800         // NSEG / VPB
#define CIN   64
#define COUT  32
#define VPB   64            // voxels per block
#define PSTR  65            // pooled LDS stride: phase-2 bank=(lv+k)%32 -> 2-way = free
#define CAP   96            // bucket capacity per block (avg 44, +6 sigma ~ 84)
#define SPILLCAP 8192       // global spill entries (normally 0 used)

// ---------------------------------------------------------------------------
// R8: unordered per-block buckets + LDS atomic scatter-max.
//   Front-end: memset(43KB) + ONE N-pass (bin). No scans, no CSR ordering.
//   Pool phase-1: stage bucket ids (coalesced), distribute rows over all 16
//   subgroups (load-balanced regardless of per-voxel skew), 4-deep batched
//   unconditional float4 loads (clamped row index -> idempotent re-merge),
//   ds_atomic_umax on monotonic uint keys. No dependent chains anywhere.
//   Phase-2 matvec: unchanged verified body (sP floats after in-place decode).
// Workspace: bCnt[10800] + spillCnt + pad + bucket[10800*96] + spill = 4.26MB.
// ---------------------------------------------------------------------------

__device__ __forceinline__ unsigned fkey(float f) {
    unsigned u = __float_as_uint(f);
    return (u & 0x80000000u) ? ~u : (u | 0x80000000u);   // monotone float->uint
}
__device__ __forceinline__ float funkey(unsigned k) {
    unsigned u = (k & 0x80000000u) ? (k ^ 0x80000000u) : ~k;
    return __uint_as_float(u);
}

__global__ __launch_bounds__(256) void bin_kernel(
    const int* __restrict__ ind,    // [N,2]
    const int* __restrict__ bidx,   // [N]
    int*       __restrict__ bCnt,   // [NBLK], zeroed
    int*       __restrict__ spillCnt,
    int*       __restrict__ bucket, // [NBLK*CAP]
    int2*      __restrict__ spill,  // [SPILLCAP]
    int N)
{
    int i = blockIdx.x * 256 + threadIdx.x;
    if (i >= N) return;
    int2 xy = ((const int2*)ind)[i];
    int seg = bidx[i] * GXGY + xy.x * 360 + xy.y;
    int blk = seg >> 6;
    int enc = (i << 6) | (seg & 63);          // i < 2^19, local voxel 6 bits
    int pos = atomicAdd(&bCnt[blk], 1);
    if (pos < CAP) {
        bucket[blk * CAP + pos] = enc;
    } else {                                   // statistically unreachable
        int sp = atomicAdd(spillCnt, 1);
        if (sp < SPILLCAP) spill[sp] = make_int2(blk, enc);
    }
}

__global__ __launch_bounds__(256) void pool_compress_kernel(
    const float* __restrict__ fea,      // [N, 64]
    const int*   __restrict__ bCnt,     // [NBLK]
    const int*   __restrict__ spillCnt,
    const int*   __restrict__ bucket,   // [NBLK*CAP]
    const int2*  __restrict__ spill,
    const float* __restrict__ W,        // [64, 32] row-major
    const float* __restrict__ bias,     // [32]
    float*       __restrict__ out)      // [B, 32, GX, GY]
{
    __shared__ unsigned sK[VPB * PSTR];   // 16.6 KB pooled keys -> floats
    __shared__ int      sOcc[VPB];
    __shared__ int      sIds[CAP];

    int tid = threadIdx.x;
    int blk = blockIdx.x;
    int vbase = blk * VPB;

    // init keys to 0 (below every real value's key) and occupancy to 0
    #pragma unroll
    for (int j = 0; j < 17; ++j) {
        int idx = tid + j * 256;
        if (idx < VPB * PSTR) sK[idx] = 0u;
    }
    if (tid < VPB) sOcc[tid] = 0;

    int nb = min(bCnt[blk], CAP);                    // block-uniform -> s_load
    if (tid < nb) sIds[tid] = bucket[blk * CAP + tid];
    __syncthreads();

    // ---- Phase 1: load-balanced scatter-max, 4-deep batched loads ----
    int sg = tid >> 4;        // subgroup 0..15 (16 lanes each)
    int sl = tid & 15;
    for (int r0 = sg; r0 < nb; r0 += 64) {
        // clamped row indices: duplicates re-merge a row into its own voxel
        int r1 = min(r0 + 16, nb - 1);
        int r2 = min(r0 + 32, nb - 1);
        int r3 = min(r0 + 48, nb - 1);
        int e0 = sIds[r0], e1 = sIds[r1], e2 = sIds[r2], e3 = sIds[r3];
        int l0 = e0 & 63, l1 = e1 & 63, l2 = e2 & 63, l3 = e3 & 63;
        // 4 independent float4 loads issue back-to-back (one latency)
        float4 t0 = ((const float4*)(fea + (size_t)(e0 >> 6) * CIN))[sl];
        float4 t1 = ((const float4*)(fea + (size_t)(e1 >> 6) * CIN))[sl];
        float4 t2 = ((const float4*)(fea + (size_t)(e2 >> 6) * CIN))[sl];
        float4 t3 = ((const float4*)(fea + (size_t)(e3 >> 6) * CIN))[sl];

        unsigned* p0 = &sK[l0 * PSTR + sl * 4];
        atomicMax(p0 + 0, fkey(t0.x)); atomicMax(p0 + 1, fkey(t0.y));
        atomicMax(p0 + 2, fkey(t0.z)); atomicMax(p0 + 3, fkey(t0.w));
        unsigned* p1 = &sK[l1 * PSTR + sl * 4];
        atomicMax(p1 + 0, fkey(t1.x)); atomicMax(p1 + 1, fkey(t1.y));
        atomicMax(p1 + 2, fkey(t1.z)); atomicMax(p1 + 3, fkey(t1.w));
        unsigned* p2 = &sK[l2 * PSTR + sl * 4];
        atomicMax(p2 + 0, fkey(t2.x)); atomicMax(p2 + 1, fkey(t2.y));
        atomicMax(p2 + 2, fkey(t2.z)); atomicMax(p2 + 3, fkey(t2.w));
        unsigned* p3 = &sK[l3 * PSTR + sl * 4];
        atomicMax(p3 + 0, fkey(t3.x)); atomicMax(p3 + 1, fkey(t3.y));
        atomicMax(p3 + 2, fkey(t3.z)); atomicMax(p3 + 3, fkey(t3.w));
        if (sl == 0) { sOcc[l0] = 1; sOcc[l1] = 1; sOcc[l2] = 1; sOcc[l3] = 1; }
    }

    // ---- spill merge (normally skipped: nsp == 0) ----
    int nsp = spillCnt[0];
    if (nsp > 0) {
        int ns = min(nsp, SPILLCAP);
        for (int j = 0; j < ns; ++j) {
            int2 e = spill[j];                        // broadcast load
            if (e.x == blk && tid < 16) {
                int lv = e.y & 63;
                float4 t = ((const float4*)(fea + (size_t)(e.y >> 6) * CIN))[tid];
                unsigned* p = &sK[lv * PSTR + tid * 4];
                atomicMax(p + 0, fkey(t.x)); atomicMax(p + 1, fkey(t.y));
                atomicMax(p + 2, fkey(t.z)); atomicMax(p + 3, fkey(t.w));
                if (tid == 0) sOcc[lv] = 1;
            }
        }
    }
    __syncthreads();

    // ---- decode keys -> floats in place (disjoint per-thread slots) ----
    float* sP = (float*)sK;
    #pragma unroll
    for (int j = 0; j < 17; ++j) {
        int idx = tid + j * 256;
        if (idx < VPB * PSTR) sP[idx] = funkey(sK[idx]);
    }
    __syncthreads();

    // ---- Phase 2 (verified body): 64x8 matvec, W via wave-uniform s_loads ----
    int wid  = tid >> 6;
    int lane = tid & 63;
    int lv = lane;                                   // voxel within block
    int g  = __builtin_amdgcn_readfirstlane(wid);    // wave-uniform SGPR
    int b  = vbase / GXGY;                           // uniform per block
    int rem = vbase - b * GXGY + lv;

    const float* Wg = W + g * 8;
    const float* bg = bias + g * 8;

    float res[8];
    if (sOcc[lv]) {
        float acc[8];
        #pragma unroll
        for (int c = 0; c < 8; ++c) acc[c] = bg[c];
        #pragma unroll 16
        for (int k = 0; k < CIN; ++k) {
            float p = sP[lv * PSTR + k];             // 2-way bank = free
            #pragma unroll
            for (int c = 0; c < 8; ++c)
                acc[c] = fmaf(p, Wg[k * COUT + c], acc[c]);
        }
        #pragma unroll
        for (int c = 0; c < 8; ++c) res[c] = fmaxf(acc[c], 0.0f);
    } else {
        #pragma unroll
        for (int c = 0; c < 8; ++c) res[c] = 0.0f;
    }

    float* op = out + (size_t)b * COUT * GXGY + (size_t)g * 8 * GXGY + rem;
    #pragma unroll
    for (int c = 0; c < 8; ++c) op[c * GXGY] = res[c];
}

extern "C" void kernel_launch(void* const* d_in, const int* in_sizes, int n_in,
                              void* d_out, int out_size, void* d_ws, size_t ws_size,
                              hipStream_t stream)
{
    const float* fea  = (const float*)d_in[0];
    const int*   ind  = (const int*)d_in[1];
    const int*   bidx = (const int*)d_in[2];
    const float* W    = (const float*)d_in[3];
    const float* bias = (const float*)d_in[4];
    float*       out  = (float*)d_out;

    int N = in_sizes[0] / CIN;  // 480000

    // ws layout (ints): bCnt[NBLK] | spillCnt | pad to 10816 | bucket[NBLK*CAP] | spill[2*SPILLCAP]
    int* bCnt     = (int*)d_ws;
    int* spillCnt = bCnt + NBLK;
    int* bucket   = bCnt + 10816;                 // 16-aligned start
    int2* spill   = (int2*)(bucket + NBLK * CAP); // 8B-aligned (even int offset)

    hipMemsetAsync(bCnt, 0, 10816 * sizeof(int), stream);   // bCnt + spillCnt + pad
    bin_kernel<<<(N + 255) / 256, 256, 0, stream>>>(ind, bidx, bCnt, spillCnt,
                                                    bucket, spill, N);
    pool_compress_kernel<<<NBLK, 256, 0, stream>>>(fea, bCnt, spillCnt, bucket,
                                                   spill, W, bias, out);
}